// Round 4
// baseline (4085.875 us; speedup 1.0000x reference)
//
#include <hip/hip_runtime.h>
#include <hip/hip_bf16.h>

// ---------------------------------------------------------------------------
// CRQ-VAE forward: encoder MLP (768->512->256->64, relu,relu,none) + 4-level
// residual VQ (K=256, e=64) with loss and codes.
// Outputs (flat): x_q [N*64] f32, rq_loss [1] f32, codes [4*N] f32.
// RVQ: fp64 vector distance ranking (exact given our residual), codebook
// pre-widened to f64 (-2*cb) so the inner loop is pure v_fma_f64.
// ---------------------------------------------------------------------------

typedef double d2 __attribute__((ext_vector_type(2)));

#define GBM 128
#define GBN 64
#define GBK 16
#define GTM 8
#define GTN 4

// C[M,N] = act(A[M,K] @ W[K,N] + bias[N]);  M%128==0, N%64==0, K%16==0
template<bool RELU>
__global__ __launch_bounds__(256) void gemm_bias(
    const float* __restrict__ A, const float* __restrict__ W,
    const float* __restrict__ bias, float* __restrict__ C,
    int M, int N, int K)
{
    __shared__ float As[GBK][GBM + 4];
    __shared__ float Bs[GBK][GBN + 4];

    const int tid = threadIdx.x;
    const int tx = tid & 15;
    const int ty = tid >> 4;
    const int col0 = blockIdx.x * GBN;
    const int row0 = blockIdx.y * GBM;

    const float* Ab = A + (size_t)row0 * K;
    const float* Wb = W + col0;

    float acc[GTM][GTN] = {};

    for (int k0 = 0; k0 < K; k0 += GBK) {
#pragma unroll
        for (int i = 0; i < 2; ++i) {
            int pos = tid + i * 256;
            int m  = pos >> 2;
            int k4 = (pos & 3) * 4;
            float4 v = *reinterpret_cast<const float4*>(Ab + (size_t)m * K + k0 + k4);
            As[k4 + 0][m] = v.x; As[k4 + 1][m] = v.y;
            As[k4 + 2][m] = v.z; As[k4 + 3][m] = v.w;
        }
        {
            int kk = tid >> 4;
            int n4 = (tid & 15) * 4;
            float4 v = *reinterpret_cast<const float4*>(Wb + (size_t)(k0 + kk) * N + n4);
            *reinterpret_cast<float4*>(&Bs[kk][n4]) = v;
        }
        __syncthreads();
#pragma unroll
        for (int kk = 0; kk < GBK; ++kk) {
            float4 a0 = *reinterpret_cast<const float4*>(&As[kk][ty * GTM]);
            float4 a1 = *reinterpret_cast<const float4*>(&As[kk][ty * GTM + 4]);
            float4 bv = *reinterpret_cast<const float4*>(&Bs[kk][tx * GTN]);
            float a[GTM] = {a0.x, a0.y, a0.z, a0.w, a1.x, a1.y, a1.z, a1.w};
            float b[GTN] = {bv.x, bv.y, bv.z, bv.w};
#pragma unroll
            for (int m = 0; m < GTM; ++m)
#pragma unroll
                for (int n = 0; n < GTN; ++n)
                    acc[m][n] = fmaf(a[m], b[n], acc[m][n]);
        }
        __syncthreads();
    }

    float bv[GTN];
#pragma unroll
    for (int n = 0; n < GTN; ++n) bv[n] = bias[col0 + tx * GTN + n];
#pragma unroll
    for (int m = 0; m < GTM; ++m) {
        int row = row0 + ty * GTM + m;
        float4 o;
        float v0 = acc[m][0] + bv[0];
        float v1 = acc[m][1] + bv[1];
        float v2 = acc[m][2] + bv[2];
        float v3 = acc[m][3] + bv[3];
        if (RELU) {
            v0 = fmaxf(v0, 0.f); v1 = fmaxf(v1, 0.f);
            v2 = fmaxf(v2, 0.f); v3 = fmaxf(v3, 0.f);
        }
        o.x = v0; o.y = v1; o.z = v2; o.w = v3;
        *reinterpret_cast<float4*>(C + (size_t)row * N + col0 + tx * GTN) = o;
    }
}

// ---------------------------------------------------------------------------
// codebook norms in fp64: cn[l*256+c] = sum_j cb[l][c][j]^2
__global__ void cb_norms(const float* __restrict__ cb, double* __restrict__ cn) {
    int c = blockIdx.x * 64 + threadIdx.x;   // 16 blocks x 64
    const float* p = cb + (size_t)c * 64;
    double s = 0.0;
#pragma unroll
    for (int j = 0; j < 64; ++j) {
        double v = (double)p[j];
        s = fma(v, v, s);
    }
    cn[c] = s;
}

// widened codebook: cbw[i] = -2 * cb[i]  (same flat [4,256,64] layout)
__global__ void build_cbw(const float* __restrict__ cb, double* __restrict__ cbw) {
    int i = blockIdx.x * 256 + threadIdx.x;   // 256 blocks -> 65536
    cbw[i] = -2.0 * (double)cb[i];
}

// ---------------------------------------------------------------------------
// RVQ v2: 64 rows per block (lane = row), 4 waves split the 256 codes
// contiguously (wave w: codes [w*64, w*64+64)). Residual in 64 f64 VGPRs
// (values always exactly f32-representable; updates rounded through f32 to
// match the reference chain). All waves redundantly maintain the residual.
__global__ __launch_bounds__(256) void rvq_v2(
    const float* __restrict__ z,       // [cur, 64] chunk-local
    const float* __restrict__ cb,      // [4,256,64] f32 (gather)
    const double* __restrict__ cbw,    // [4,256,64] f64 (-2*cb)
    const double* __restrict__ cn,     // [1024] f64 code norms
    float* __restrict__ xq,            // d_out base [N,64]
    float* __restrict__ codes,         // d_out codes base [4,N]
    double* __restrict__ partials,     // [N/64]
    int row0, int Ntot)
{
    __shared__ double red_d[4][64];
    __shared__ int    red_i[4][64];

    const int tid  = threadIdx.x;
    const int lane = tid & 63;
    const int w    = tid >> 6;
    const int blk  = blockIdx.x;
    const int grow0 = row0 + blk * 64;

    // load this lane's row of z into f64 registers (each wave redundantly)
    double rd[64];
    const float* zr = z + (size_t)(blk * 64 + lane) * 64;
#pragma unroll
    for (int j4 = 0; j4 < 16; ++j4) {
        float4 v = *reinterpret_cast<const float4*>(zr + j4 * 4);
        rd[j4 * 4 + 0] = (double)v.x; rd[j4 * 4 + 1] = (double)v.y;
        rd[j4 * 4 + 2] = (double)v.z; rd[j4 * 4 + 3] = (double)v.w;
    }

    double sse = 0.0;

    for (int lv = 0; lv < 4; ++lv) {
        // ---- distance scan: rank = cn_c - 2*dot(r,c)  (sr dropped) ----
        const double* cwl = cbw + ((size_t)lv * 256 + w * 64) * 64;
        const double* cnl = cn + lv * 256 + w * 64;

        double dmin = 1e300;
        int    imin = 0;
        for (int c = 0; c < 64; ++c) {
            const double* cp = cwl + c * 64;   // wave-uniform address
            double a0 = cnl[c], a1 = 0.0, a2 = 0.0, a3 = 0.0;
#pragma unroll
            for (int q = 0; q < 8; ++q) {
                d2 c01 = *reinterpret_cast<const d2*>(cp + q * 8 + 0);
                d2 c23 = *reinterpret_cast<const d2*>(cp + q * 8 + 2);
                d2 c45 = *reinterpret_cast<const d2*>(cp + q * 8 + 4);
                d2 c67 = *reinterpret_cast<const d2*>(cp + q * 8 + 6);
                a0 = fma(c01[0], rd[q * 8 + 0], a0);
                a1 = fma(c01[1], rd[q * 8 + 1], a1);
                a2 = fma(c23[0], rd[q * 8 + 2], a2);
                a3 = fma(c23[1], rd[q * 8 + 3], a3);
                a0 = fma(c45[0], rd[q * 8 + 4], a0);
                a1 = fma(c45[1], rd[q * 8 + 5], a1);
                a2 = fma(c67[0], rd[q * 8 + 6], a2);
                a3 = fma(c67[1], rd[q * 8 + 7], a3);
            }
            double d = (a0 + a1) + (a2 + a3);
            if (d < dmin) { dmin = d; imin = w * 64 + c; }   // first-min: low idx
        }

        // ---- cross-wave argmin combine (all waves compute the result) ----
        red_d[w][lane] = dmin;
        red_i[w][lane] = imin;
        __syncthreads();
        double bd = red_d[0][lane];
        int    bi = red_i[0][lane];
#pragma unroll
        for (int ww = 1; ww < 4; ++ww) {
            double dd = red_d[ww][lane];
            int    ii = red_i[ww][lane];
            if (dd < bd || (dd == bd && ii < bi)) { bd = dd; bi = ii; }
        }
        __syncthreads();   // red_* fully consumed before next level reuses it

        // ---- gather q (f32), fp32 residual update (matches ref), loss ----
        const float* qp = cb + ((size_t)lv * 256 + bi) * 64;
        double lsse = 0.0;
#pragma unroll
        for (int j4 = 0; j4 < 16; ++j4) {
            float4 qv = *reinterpret_cast<const float4*>(qp + j4 * 4);
            float r0 = (float)rd[j4 * 4 + 0];
            float r1 = (float)rd[j4 * 4 + 1];
            float r2 = (float)rd[j4 * 4 + 2];
            float r3 = (float)rd[j4 * 4 + 3];
            float e0 = qv.x - r0, e1 = qv.y - r1;
            float e2 = qv.z - r2, e3 = qv.w - r3;
            lsse = fma((double)e0, (double)e0, lsse);
            lsse = fma((double)e1, (double)e1, lsse);
            lsse = fma((double)e2, (double)e2, lsse);
            lsse = fma((double)e3, (double)e3, lsse);
            rd[j4 * 4 + 0] = (double)(r0 - qv.x);
            rd[j4 * 4 + 1] = (double)(r1 - qv.y);
            rd[j4 * 4 + 2] = (double)(r2 - qv.z);
            rd[j4 * 4 + 3] = (double)(r3 - qv.w);
        }
        sse += lsse;

        if (w == 0)
            codes[(size_t)lv * Ntot + grow0 + lane] = (float)bi;
    }

    // ---- x_q = z - r_final ; loss partial (wave 0 only) ----
    if (w == 0) {
        size_t base = (size_t)(grow0 + lane) * 64;
#pragma unroll
        for (int j4 = 0; j4 < 16; ++j4) {
            float4 zv = *reinterpret_cast<const float4*>(zr + j4 * 4);
            float4 o;
            o.x = zv.x - (float)rd[j4 * 4 + 0];
            o.y = zv.y - (float)rd[j4 * 4 + 1];
            o.z = zv.z - (float)rd[j4 * 4 + 2];
            o.w = zv.w - (float)rd[j4 * 4 + 3];
            *reinterpret_cast<float4*>(xq + base + j4 * 4) = o;
        }
        double s = sse;
#pragma unroll
        for (int off = 32; off > 0; off >>= 1) {
            union { double d; int i[2]; } u; u.d = s;
            u.i[0] = __shfl_down(u.i[0], off, 64);
            u.i[1] = __shfl_down(u.i[1], off, 64);
            s += u.d;
        }
        if (lane == 0) partials[grow0 >> 6] = s;
    }
}

// ---------------------------------------------------------------------------
__global__ void loss_final(const double* __restrict__ partials, int n,
                           float* __restrict__ out, double scale) {
    __shared__ double s[256];
    double acc = 0.0;
    for (int i = threadIdx.x; i < n; i += 256) acc += partials[i];
    s[threadIdx.x] = acc;
    __syncthreads();
    for (int off = 128; off > 0; off >>= 1) {
        if ((int)threadIdx.x < off) s[threadIdx.x] += s[threadIdx.x + off];
        __syncthreads();
    }
    if (threadIdx.x == 0) *out = (float)(s[0] * scale);
}

// ---------------------------------------------------------------------------
extern "C" void kernel_launch(void* const* d_in, const int* in_sizes, int n_in,
                              void* d_out, int out_size, void* d_ws, size_t ws_size,
                              hipStream_t stream) {
    const float* x  = (const float*)d_in[0];
    const float* W0 = (const float*)d_in[1];
    const float* b0 = (const float*)d_in[2];
    const float* W1 = (const float*)d_in[3];
    const float* b1 = (const float*)d_in[4];
    const float* W2 = (const float*)d_in[5];
    const float* b2 = (const float*)d_in[6];
    const float* cb = (const float*)d_in[7];

    const int N = in_sizes[0] / 768;

    float* out   = (float*)d_out;
    float* xq    = out;                      // [N*64]
    float* loss  = out + (size_t)N * 64;     // [1]
    float* codes = loss + 1;                 // [4*N]

    const int nblk_total = N / 64;
    // tail (float units): cbw 65536 d + cn 1024 d + partials nblk d + pad
    const size_t tail_floats = 131072 + 2048 + 2 * (size_t)nblk_total + 64;

    size_t avail = ws_size / 4;
    avail = (avail > tail_floats) ? (avail - tail_floats) : 0;
    int Nc = (int)(avail / 832);
    Nc = (Nc / 128) * 128;
    if (Nc > N) Nc = N;
    if (Nc < 128) Nc = 128;

    float* ws = (float*)d_ws;
    float* h0 = ws;
    float* h1 = h0 + (size_t)Nc * 512;
    float* z  = h1 + (size_t)Nc * 256;
    double* cbw      = (double*)(ws + (size_t)Nc * 832);  // 16B-aligned (Nc%128==0)
    double* cn       = cbw + 65536;
    double* partials = cn + 1024;

    cb_norms <<<16, 64, 0, stream>>>(cb, cn);
    build_cbw<<<256, 256, 0, stream>>>(cb, cbw);

    for (int r0 = 0; r0 < N; r0 += Nc) {
        int cur = (N - r0 < Nc) ? (N - r0) : Nc;
        gemm_bias<true ><<<dim3(512 / GBN, cur / GBM), 256, 0, stream>>>(
            x + (size_t)r0 * 768, W0, b0, h0, cur, 512, 768);
        gemm_bias<true ><<<dim3(256 / GBN, cur / GBM), 256, 0, stream>>>(
            h0, W1, b1, h1, cur, 256, 512);
        gemm_bias<false><<<dim3( 64 / GBN, cur / GBM), 256, 0, stream>>>(
            h1, W2, b2, z, cur, 64, 256);
        rvq_v2<<<cur / 64, 256, 0, stream>>>(
            z, cb, cbw, cn, xq, codes, partials, r0, N);
    }

    loss_final<<<1, 256, 0, stream>>>(partials, nblk_total, loss,
                                      1.25 / (4.0 * (double)N * 64.0));
}

// Round 5
// 3998.785 us; speedup vs baseline: 1.0218x; 1.0218x over previous
//
#include <hip/hip_runtime.h>
#include <hip/hip_bf16.h>

// ---------------------------------------------------------------------------
// CRQ-VAE forward: encoder MLP (768->512->256->64, relu,relu,none) + 4-level
// residual VQ (K=256, e=64) with loss and codes.
// Outputs (flat): x_q [N*64] f32, rq_loss [1] f32, codes [4*N] f32.
// RVQ: f32 register-resident distance scan (top-2 per row) + exact fp64
// verification of the two candidates + rare exact fp64 rescue. Final code
// selection provably equals exact-fp64 argmin (lowest index on ties), i.e.
// identical to the R2/R4 passing kernels.
// ---------------------------------------------------------------------------

typedef double d2v __attribute__((ext_vector_type(2)));

#define GBM 128
#define GBN 64
#define GBK 16
#define GTM 8
#define GTN 4

// C[M,N] = act(A[M,K] @ W[K,N] + bias[N]);  M%128==0, N%64==0, K%16==0
template<bool RELU>
__global__ __launch_bounds__(256) void gemm_bias(
    const float* __restrict__ A, const float* __restrict__ W,
    const float* __restrict__ bias, float* __restrict__ C,
    int M, int N, int K)
{
    __shared__ float As[GBK][GBM + 4];
    __shared__ float Bs[GBK][GBN + 4];

    const int tid = threadIdx.x;
    const int tx = tid & 15;
    const int ty = tid >> 4;
    const int col0 = blockIdx.x * GBN;
    const int row0 = blockIdx.y * GBM;

    const float* Ab = A + (size_t)row0 * K;
    const float* Wb = W + col0;

    float acc[GTM][GTN] = {};

    for (int k0 = 0; k0 < K; k0 += GBK) {
#pragma unroll
        for (int i = 0; i < 2; ++i) {
            int pos = tid + i * 256;
            int m  = pos >> 2;
            int k4 = (pos & 3) * 4;
            float4 v = *reinterpret_cast<const float4*>(Ab + (size_t)m * K + k0 + k4);
            As[k4 + 0][m] = v.x; As[k4 + 1][m] = v.y;
            As[k4 + 2][m] = v.z; As[k4 + 3][m] = v.w;
        }
        {
            int kk = tid >> 4;
            int n4 = (tid & 15) * 4;
            float4 v = *reinterpret_cast<const float4*>(Wb + (size_t)(k0 + kk) * N + n4);
            *reinterpret_cast<float4*>(&Bs[kk][n4]) = v;
        }
        __syncthreads();
#pragma unroll
        for (int kk = 0; kk < GBK; ++kk) {
            float4 a0 = *reinterpret_cast<const float4*>(&As[kk][ty * GTM]);
            float4 a1 = *reinterpret_cast<const float4*>(&As[kk][ty * GTM + 4]);
            float4 bv = *reinterpret_cast<const float4*>(&Bs[kk][tx * GTN]);
            float a[GTM] = {a0.x, a0.y, a0.z, a0.w, a1.x, a1.y, a1.z, a1.w};
            float b[GTN] = {bv.x, bv.y, bv.z, bv.w};
#pragma unroll
            for (int m = 0; m < GTM; ++m)
#pragma unroll
                for (int n = 0; n < GTN; ++n)
                    acc[m][n] = fmaf(a[m], b[n], acc[m][n]);
        }
        __syncthreads();
    }

    float bv[GTN];
#pragma unroll
    for (int n = 0; n < GTN; ++n) bv[n] = bias[col0 + tx * GTN + n];
#pragma unroll
    for (int m = 0; m < GTM; ++m) {
        int row = row0 + ty * GTM + m;
        float4 o;
        float v0 = acc[m][0] + bv[0];
        float v1 = acc[m][1] + bv[1];
        float v2 = acc[m][2] + bv[2];
        float v3 = acc[m][3] + bv[3];
        if (RELU) {
            v0 = fmaxf(v0, 0.f); v1 = fmaxf(v1, 0.f);
            v2 = fmaxf(v2, 0.f); v3 = fmaxf(v3, 0.f);
        }
        o.x = v0; o.y = v1; o.z = v2; o.w = v3;
        *reinterpret_cast<float4*>(C + (size_t)row * N + col0 + tx * GTN) = o;
    }
}

// ---------------------------------------------------------------------------
// codebook norms: cn64[c] (fp64) and cnf[c] (f32 rounding of cn64)
__global__ void cb_norms(const float* __restrict__ cb,
                         double* __restrict__ cn64, float* __restrict__ cnf) {
    int c = blockIdx.x * 64 + threadIdx.x;   // 16 blocks x 64
    const float* p = cb + (size_t)c * 64;
    double s = 0.0;
#pragma unroll
    for (int j = 0; j < 64; ++j) {
        double v = (double)p[j];
        s = fma(v, v, s);
    }
    cn64[c] = s;
    cnf[c]  = (float)s;
}

// widened codebook: cbw[i] = -2 * cb[i]  (same flat [4,256,64] layout, fp64)
__global__ void build_cbw(const float* __restrict__ cb, double* __restrict__ cbw) {
    int i = blockIdx.x * 256 + threadIdx.x;   // 256 blocks -> 65536
    cbw[i] = -2.0 * (double)cb[i];
}

// ---------------------------------------------------------------------------
#define EGUARD 4e-3

// RVQ v3: 64 rows/block (lane = row), 4 waves split the 256 codes.
// f32 scan -> top2 -> fp64 verify -> rare fp64 rescue.
__global__ __launch_bounds__(256, 2) void rvq_v3(
    const float* __restrict__ z,       // [cur, 64] chunk-local
    const float* __restrict__ cbf,     // [4,256,64] f32 codebook
    const double* __restrict__ cbw,    // [4,256,64] f64 (-2*cb)
    const double* __restrict__ cn64,   // [1024] f64 code norms
    const float* __restrict__ cnf,     // [1024] f32 code norms
    float* __restrict__ xq,            // d_out base [N,64]
    float* __restrict__ codes,         // d_out codes base [4,N]
    double* __restrict__ partials,     // [N/64]
    int row0, int Ntot)
{
    __shared__ float sd1[4][64];
    __shared__ float sd2[4][64];
    __shared__ int   si1[4][64];
    __shared__ int   si2[4][64];
    __shared__ int   sbi[64];

    const int tid  = threadIdx.x;
    const int lane = tid & 63;
    const int w    = tid >> 6;
    const int blk  = blockIdx.x;
    const int grow0 = row0 + blk * 64;

    // this lane's row, f32 registers (exact reference residual chain)
    float rd[64];
    const float* zr = z + (size_t)(blk * 64 + lane) * 64;
#pragma unroll
    for (int q = 0; q < 16; ++q) {
        float4 v = *reinterpret_cast<const float4*>(zr + q * 4);
        rd[q * 4 + 0] = v.x; rd[q * 4 + 1] = v.y;
        rd[q * 4 + 2] = v.z; rd[q * 4 + 3] = v.w;
    }

    double sse = 0.0;   // wave 0 only

    for (int lv = 0; lv < 4; ++lv) {
        // ------------- f32 scan over this wave's 64 codes, top-2 -------------
        const float* cwl = cbf + ((size_t)lv * 256 + (size_t)w * 64) * 64;
        const float* cnl = cnf + lv * 256 + w * 64;

        float4 bufA[16], bufB[16];
#pragma unroll
        for (int q = 0; q < 16; ++q)
            bufA[q] = *reinterpret_cast<const float4*>(cwl + q * 4);

        float d1 = 3.4e38f, dd2 = 3.4e38f;
        int   i1 = 0,       i2 = 0;

        for (int c = 0; c < 64; c += 2) {
            // prefetch code c+1
#pragma unroll
            for (int q = 0; q < 16; ++q)
                bufB[q] = *reinterpret_cast<const float4*>(cwl + (c + 1) * 64 + q * 4);
            // compute with bufA (code c)
            {
                float a0 = 0.f, a1 = 0.f, a2 = 0.f, a3 = 0.f;
#pragma unroll
                for (int q = 0; q < 16; ++q) {
                    float4 cv = bufA[q];
                    a0 = fmaf(cv.x, rd[q * 4 + 0], a0);
                    a1 = fmaf(cv.y, rd[q * 4 + 1], a1);
                    a2 = fmaf(cv.z, rd[q * 4 + 2], a2);
                    a3 = fmaf(cv.w, rd[q * 4 + 3], a3);
                }
                float d = fmaf(-2.f, (a0 + a1) + (a2 + a3), cnl[c]);
                int code = w * 64 + c;
                if (d < d1) { dd2 = d1; i2 = i1; d1 = d; i1 = code; }
                else if (d < dd2) { dd2 = d; i2 = code; }
            }
            // prefetch code c+2 (clamped reload at tail, harmless)
            int cn2 = (c + 2 < 64) ? (c + 2) : 63;
#pragma unroll
            for (int q = 0; q < 16; ++q)
                bufA[q] = *reinterpret_cast<const float4*>(cwl + cn2 * 64 + q * 4);
            // compute with bufB (code c+1)
            {
                float a0 = 0.f, a1 = 0.f, a2 = 0.f, a3 = 0.f;
#pragma unroll
                for (int q = 0; q < 16; ++q) {
                    float4 cv = bufB[q];
                    a0 = fmaf(cv.x, rd[q * 4 + 0], a0);
                    a1 = fmaf(cv.y, rd[q * 4 + 1], a1);
                    a2 = fmaf(cv.z, rd[q * 4 + 2], a2);
                    a3 = fmaf(cv.w, rd[q * 4 + 3], a3);
                }
                float d = fmaf(-2.f, (a0 + a1) + (a2 + a3), cnl[c + 1]);
                int code = w * 64 + c + 1;
                if (d < d1) { dd2 = d1; i2 = i1; d1 = d; i1 = code; }
                else if (d < dd2) { dd2 = d; i2 = code; }
            }
        }

        sd1[w][lane] = d1;  si1[w][lane] = i1;
        sd2[w][lane] = dd2; si2[w][lane] = i2;
        __syncthreads();   // B1

        // ------------- wave 0: combine, fp64 verify, rare rescue -------------
        if (w == 0) {
            float bd1 = sd1[0][lane]; int bi1 = si1[0][lane]; int wstar = 0;
#pragma unroll
            for (int ww = 1; ww < 4; ++ww) {
                float dd = sd1[ww][lane]; int ii = si1[ww][lane];
                if (dd < bd1 || (dd == bd1 && ii < bi1)) { bd1 = dd; bi1 = ii; wstar = ww; }
            }
            float d2g = 3.4e38f; int i2g = 0;
#pragma unroll
            for (int ww = 0; ww < 4; ++ww) {
                float dd = (ww == wstar) ? sd2[ww][lane] : sd1[ww][lane];
                int   ii = (ww == wstar) ? si2[ww][lane] : si1[ww][lane];
                if (dd < d2g) { d2g = dd; i2g = ii; }
            }

            // exact fp64 rank of both candidates
            double rdd[64];
#pragma unroll
            for (int j = 0; j < 64; ++j) rdd[j] = (double)rd[j];

            const double* p1 = cbw + ((size_t)lv * 256 + bi1) * 64;
            const double* p2 = cbw + ((size_t)lv * 256 + i2g) * 64;
            double R1 = cn64[lv * 256 + bi1];
            double R2 = cn64[lv * 256 + i2g];
#pragma unroll
            for (int j = 0; j < 64; ++j) R1 = fma(p1[j], rdd[j], R1);
#pragma unroll
            for (int j = 0; j < 64; ++j) R2 = fma(p2[j], rdd[j], R2);

            int    ci; double Rw;
            if (R1 < R2 || (R1 == R2 && bi1 < i2g)) { ci = bi1; Rw = R1; }
            else                                    { ci = i2g; Rw = R2; }

            // safety: every other code c has D_c >= d2g, so R_c >= d2g - E.
            if (!(Rw < (double)d2g - EGUARD)) {
                // exact full rescan (rare)
                double dmin = 1e300; int imin = 0;
                const double* cl = cbw + (size_t)lv * 256 * 64;
                const double* nl = cn64 + lv * 256;
                for (int c = 0; c < 256; ++c) {
                    const double* cp = cl + c * 64;
                    double a0 = nl[c], a1 = 0.0, a2 = 0.0, a3 = 0.0;
#pragma unroll
                    for (int q = 0; q < 16; ++q) {
                        d2v c01 = *reinterpret_cast<const d2v*>(cp + q * 4 + 0);
                        d2v c23 = *reinterpret_cast<const d2v*>(cp + q * 4 + 2);
                        a0 = fma(c01[0], rdd[q * 4 + 0], a0);
                        a1 = fma(c01[1], rdd[q * 4 + 1], a1);
                        a2 = fma(c23[0], rdd[q * 4 + 2], a2);
                        a3 = fma(c23[1], rdd[q * 4 + 3], a3);
                    }
                    double d = (a0 + a1) + (a2 + a3);
                    if (d < dmin) { dmin = d; imin = c; }
                }
                ci = imin;
            }

            sbi[lane] = ci;
            codes[(size_t)lv * Ntot + grow0 + lane] = (float)ci;
        }
        __syncthreads();   // B2

        // ------------- all waves: gather q, update residual (f32) -----------
        {
            int bi = sbi[lane];
            const float* qp = cbf + ((size_t)lv * 256 + bi) * 64;
            double lsse = 0.0;
#pragma unroll
            for (int q = 0; q < 16; ++q) {
                float4 qv = *reinterpret_cast<const float4*>(qp + q * 4);
                float r0 = rd[q * 4 + 0], r1 = rd[q * 4 + 1];
                float r2 = rd[q * 4 + 2], r3 = rd[q * 4 + 3];
                if (w == 0) {
                    float e0 = qv.x - r0, e1 = qv.y - r1;
                    float e2 = qv.z - r2, e3 = qv.w - r3;
                    lsse = fma((double)e0, (double)e0, lsse);
                    lsse = fma((double)e1, (double)e1, lsse);
                    lsse = fma((double)e2, (double)e2, lsse);
                    lsse = fma((double)e3, (double)e3, lsse);
                }
                rd[q * 4 + 0] = r0 - qv.x; rd[q * 4 + 1] = r1 - qv.y;
                rd[q * 4 + 2] = r2 - qv.z; rd[q * 4 + 3] = r3 - qv.w;
            }
            if (w == 0) sse += lsse;
        }
        // no barrier needed here: sd*/sbi for next level are rewritten only
        // after B1/B2 of the next iteration.
    }

    // ---- x_q = z - r_final ; loss partial (wave 0 only) ----
    if (w == 0) {
        size_t base = (size_t)(grow0 + lane) * 64;
#pragma unroll
        for (int q = 0; q < 16; ++q) {
            float4 zv = *reinterpret_cast<const float4*>(zr + q * 4);
            float4 o;
            o.x = zv.x - rd[q * 4 + 0];
            o.y = zv.y - rd[q * 4 + 1];
            o.z = zv.z - rd[q * 4 + 2];
            o.w = zv.w - rd[q * 4 + 3];
            *reinterpret_cast<float4*>(xq + base + q * 4) = o;
        }
        double s = sse;
#pragma unroll
        for (int off = 32; off > 0; off >>= 1) {
            union { double d; int i[2]; } u; u.d = s;
            u.i[0] = __shfl_down(u.i[0], off, 64);
            u.i[1] = __shfl_down(u.i[1], off, 64);
            s += u.d;
        }
        if (lane == 0) partials[grow0 >> 6] = s;
    }
}

// ---------------------------------------------------------------------------
__global__ void loss_final(const double* __restrict__ partials, int n,
                           float* __restrict__ out, double scale) {
    __shared__ double s[256];
    double acc = 0.0;
    for (int i = threadIdx.x; i < n; i += 256) acc += partials[i];
    s[threadIdx.x] = acc;
    __syncthreads();
    for (int off = 128; off > 0; off >>= 1) {
        if ((int)threadIdx.x < off) s[threadIdx.x] += s[threadIdx.x + off];
        __syncthreads();
    }
    if (threadIdx.x == 0) *out = (float)(s[0] * scale);
}

// ---------------------------------------------------------------------------
extern "C" void kernel_launch(void* const* d_in, const int* in_sizes, int n_in,
                              void* d_out, int out_size, void* d_ws, size_t ws_size,
                              hipStream_t stream) {
    const float* x  = (const float*)d_in[0];
    const float* W0 = (const float*)d_in[1];
    const float* b0 = (const float*)d_in[2];
    const float* W1 = (const float*)d_in[3];
    const float* b1 = (const float*)d_in[4];
    const float* W2 = (const float*)d_in[5];
    const float* b2 = (const float*)d_in[6];
    const float* cb = (const float*)d_in[7];

    const int N = in_sizes[0] / 768;

    float* out   = (float*)d_out;
    float* xq    = out;                      // [N*64]
    float* loss  = out + (size_t)N * 64;     // [1]
    float* codes = loss + 1;                 // [4*N]

    const int nblk_total = N / 64;
    // tail (float units): cbw 65536 dbl + cn64 1024 dbl + partials nblk dbl
    //                     + cnf 1024 f + pad
    const size_t tail_floats = 131072 + 2048 + 2 * (size_t)nblk_total + 1024 + 64;

    size_t avail = ws_size / 4;
    avail = (avail > tail_floats) ? (avail - tail_floats) : 0;
    int Nc = (int)(avail / 832);
    Nc = (Nc / 128) * 128;
    if (Nc > N) Nc = N;
    if (Nc < 128) Nc = 128;

    float* ws = (float*)d_ws;
    float* h0 = ws;
    float* h1 = h0 + (size_t)Nc * 512;
    float* z  = h1 + (size_t)Nc * 256;
    double* cbw      = (double*)(ws + (size_t)Nc * 832);  // 16B-aligned (Nc%128==0)
    double* cn64     = cbw + 65536;
    double* partials = cn64 + 1024;
    float*  cnf      = (float*)(partials + nblk_total);

    cb_norms <<<16, 64, 0, stream>>>(cb, cn64, cnf);
    build_cbw<<<256, 256, 0, stream>>>(cb, cbw);

    for (int r0 = 0; r0 < N; r0 += Nc) {
        int cur = (N - r0 < Nc) ? (N - r0) : Nc;
        gemm_bias<true ><<<dim3(512 / GBN, cur / GBM), 256, 0, stream>>>(
            x + (size_t)r0 * 768, W0, b0, h0, cur, 512, 768);
        gemm_bias<true ><<<dim3(256 / GBN, cur / GBM), 256, 0, stream>>>(
            h0, W1, b1, h1, cur, 256, 512);
        gemm_bias<false><<<dim3( 64 / GBN, cur / GBM), 256, 0, stream>>>(
            h1, W2, b2, z, cur, 64, 256);
        rvq_v3<<<cur / 64, 256, 0, stream>>>(
            z, cb, cbw, cn64, cnf, xq, codes, partials, r0, N);
    }

    loss_final<<<1, 256, 0, stream>>>(partials, nblk_total, loss,
                                      1.25 / (4.0 * (double)N * 64.0));
}

// Round 6
// 3195.874 us; speedup vs baseline: 1.2785x; 1.2512x over previous
//
#include <hip/hip_runtime.h>
#include <hip/hip_bf16.h>

// ---------------------------------------------------------------------------
// CRQ-VAE forward: encoder MLP (768->512->256->64, relu,relu,none) + 4-level
// residual VQ (K=256, e=64) with loss and codes.
// Outputs (flat): x_q [N*64] f32, rq_loss [1] f32, codes [4*N] f32.
// RVQ v4: f32 register scan (top-2/lane, no spills) + tiered fp64 exact
// verification (top-2 -> 8-candidate -> full rescan). Code selection provably
// equals exact-fp64 argmin with lowest-index ties (R2/R4 semantics).
// ---------------------------------------------------------------------------

typedef double d2v __attribute__((ext_vector_type(2)));

#define GBM 128
#define GBN 64
#define GBK 16
#define GTM 8
#define GTN 4

// C[M,N] = act(A[M,K] @ W[K,N] + bias[N]);  M%128==0, N%64==0, K%16==0
template<bool RELU>
__global__ __launch_bounds__(256) void gemm_bias(
    const float* __restrict__ A, const float* __restrict__ W,
    const float* __restrict__ bias, float* __restrict__ C,
    int M, int N, int K)
{
    __shared__ float As[GBK][GBM + 4];
    __shared__ float Bs[GBK][GBN + 4];

    const int tid = threadIdx.x;
    const int tx = tid & 15;
    const int ty = tid >> 4;
    const int col0 = blockIdx.x * GBN;
    const int row0 = blockIdx.y * GBM;

    const float* Ab = A + (size_t)row0 * K;
    const float* Wb = W + col0;

    float acc[GTM][GTN] = {};

    for (int k0 = 0; k0 < K; k0 += GBK) {
#pragma unroll
        for (int i = 0; i < 2; ++i) {
            int pos = tid + i * 256;
            int m  = pos >> 2;
            int k4 = (pos & 3) * 4;
            float4 v = *reinterpret_cast<const float4*>(Ab + (size_t)m * K + k0 + k4);
            As[k4 + 0][m] = v.x; As[k4 + 1][m] = v.y;
            As[k4 + 2][m] = v.z; As[k4 + 3][m] = v.w;
        }
        {
            int kk = tid >> 4;
            int n4 = (tid & 15) * 4;
            float4 v = *reinterpret_cast<const float4*>(Wb + (size_t)(k0 + kk) * N + n4);
            *reinterpret_cast<float4*>(&Bs[kk][n4]) = v;
        }
        __syncthreads();
#pragma unroll
        for (int kk = 0; kk < GBK; ++kk) {
            float4 a0 = *reinterpret_cast<const float4*>(&As[kk][ty * GTM]);
            float4 a1 = *reinterpret_cast<const float4*>(&As[kk][ty * GTM + 4]);
            float4 bv = *reinterpret_cast<const float4*>(&Bs[kk][tx * GTN]);
            float a[GTM] = {a0.x, a0.y, a0.z, a0.w, a1.x, a1.y, a1.z, a1.w};
            float b[GTN] = {bv.x, bv.y, bv.z, bv.w};
#pragma unroll
            for (int m = 0; m < GTM; ++m)
#pragma unroll
                for (int n = 0; n < GTN; ++n)
                    acc[m][n] = fmaf(a[m], b[n], acc[m][n]);
        }
        __syncthreads();
    }

    float bv[GTN];
#pragma unroll
    for (int n = 0; n < GTN; ++n) bv[n] = bias[col0 + tx * GTN + n];
#pragma unroll
    for (int m = 0; m < GTM; ++m) {
        int row = row0 + ty * GTM + m;
        float4 o;
        float v0 = acc[m][0] + bv[0];
        float v1 = acc[m][1] + bv[1];
        float v2 = acc[m][2] + bv[2];
        float v3 = acc[m][3] + bv[3];
        if (RELU) {
            v0 = fmaxf(v0, 0.f); v1 = fmaxf(v1, 0.f);
            v2 = fmaxf(v2, 0.f); v3 = fmaxf(v3, 0.f);
        }
        o.x = v0; o.y = v1; o.z = v2; o.w = v3;
        *reinterpret_cast<float4*>(C + (size_t)row * N + col0 + tx * GTN) = o;
    }
}

// ---------------------------------------------------------------------------
// codebook norms: cn64[c] (fp64) and cnf[c] (f32 rounding of cn64)
__global__ void cb_norms(const float* __restrict__ cb,
                         double* __restrict__ cn64, float* __restrict__ cnf) {
    int c = blockIdx.x * 64 + threadIdx.x;   // 16 blocks x 64
    const float* p = cb + (size_t)c * 64;
    double s = 0.0;
#pragma unroll
    for (int j = 0; j < 64; ++j) {
        double v = (double)p[j];
        s = fma(v, v, s);
    }
    cn64[c] = s;
    cnf[c]  = (float)s;
}

// widened codebook: cbw[i] = -2 * cb[i]  (same flat [4,256,64] layout, fp64)
__global__ void build_cbw(const float* __restrict__ cb, double* __restrict__ cbw) {
    int i = blockIdx.x * 256 + threadIdx.x;   // 256 blocks -> 65536
    cbw[i] = -2.0 * (double)cb[i];
}

// ---------------------------------------------------------------------------
#define EGUARD 1e-3   // >= 2.5x worst-case f32 scan error bound (~4e-4)

// exact fp64 rank of code cc against residual rd[] (on-the-fly widening)
__device__ inline double rank64(const double* __restrict__ cbw,
                                const double* __restrict__ cn64,
                                int base, int cc, const float* rd) {
    const double* p = cbw + (size_t)(base + cc) * 64;
    double R = cn64[base + cc];
#pragma unroll 8
    for (int j = 0; j < 64; ++j)
        R = fma(p[j], (double)rd[j], R);
    return R;
}

// RVQ v4: 64 rows/block (lane = row), 4 waves split the 256 codes.
__global__ __launch_bounds__(256) void rvq_v4(
    const float* __restrict__ z,       // [cur, 64] chunk-local
    const float* __restrict__ cbf,     // [4,256,64] f32 codebook
    const double* __restrict__ cbw,    // [4,256,64] f64 (-2*cb)
    const double* __restrict__ cn64,   // [1024] f64 code norms
    const float* __restrict__ cnf,     // [1024] f32 code norms
    float* __restrict__ xq,            // d_out base [N,64]
    float* __restrict__ codes,         // d_out codes base [4,N]
    double* __restrict__ partials,     // [N/64]
    int row0, int Ntot)
{
    __shared__ float sd1[4][64];
    __shared__ float sd2[4][64];
    __shared__ int   si1[4][64];
    __shared__ int   si2[4][64];

    const int tid  = threadIdx.x;
    const int lane = tid & 63;
    const int w    = tid >> 6;
    const int wu   = __builtin_amdgcn_readfirstlane(w);   // wave-uniform
    const int blk  = blockIdx.x;
    const int grow0 = row0 + blk * 64;

    // this lane's row, f32 registers (exact reference residual chain)
    float rd[64];
    const float* zr = z + (size_t)(blk * 64 + lane) * 64;
#pragma unroll
    for (int q = 0; q < 16; ++q) {
        float4 v = *reinterpret_cast<const float4*>(zr + q * 4);
        rd[q * 4 + 0] = v.x; rd[q * 4 + 1] = v.y;
        rd[q * 4 + 2] = v.z; rd[q * 4 + 3] = v.w;
    }

    double sse = 0.0;   // wave 0 only

    for (int lv = 0; lv < 4; ++lv) {
        const int cbase = lv * 256;
        __syncthreads();   // protect sd*/si* reuse across levels

        // ---------- f32 scan over this wave's 64 codes, top-2/lane ----------
        const float* cwl = cbf + (size_t)(cbase + wu * 64) * 64;
        const float* cnl = cnf + cbase + wu * 64;

        float d1 = 3.4e38f, d2 = 3.4e38f;
        int   i1 = 0,       i2 = 0;

#pragma unroll 1
        for (int c = 0; c < 64; ++c) {
            const float* cp = cwl + c * 64;
            // 8 independent 8-term fma chains (error <= ~4e-4 worst case)
            float a0 = 0.f, a1 = 0.f, a2 = 0.f, a3 = 0.f;
            float a4 = 0.f, a5 = 0.f, a6 = 0.f, a7 = 0.f;
#pragma unroll
            for (int q = 0; q < 8; ++q) {
                float4 va = *reinterpret_cast<const float4*>(cp + q * 8);
                float4 vb = *reinterpret_cast<const float4*>(cp + q * 8 + 4);
                float t = 0.f;
                t = fmaf(va.x, rd[q * 8 + 0], t);
                t = fmaf(va.y, rd[q * 8 + 1], t);
                t = fmaf(va.z, rd[q * 8 + 2], t);
                t = fmaf(va.w, rd[q * 8 + 3], t);
                t = fmaf(vb.x, rd[q * 8 + 4], t);
                t = fmaf(vb.y, rd[q * 8 + 5], t);
                t = fmaf(vb.z, rd[q * 8 + 6], t);
                t = fmaf(vb.w, rd[q * 8 + 7], t);
                if (q == 0) a0 = t; else if (q == 1) a1 = t;
                else if (q == 2) a2 = t; else if (q == 3) a3 = t;
                else if (q == 4) a4 = t; else if (q == 5) a5 = t;
                else if (q == 6) a6 = t; else a7 = t;
            }
            float dot = ((a0 + a1) + (a2 + a3)) + ((a4 + a5) + (a6 + a7));
            float d = fmaf(-2.f, dot, cnl[c]);
            int code = wu * 64 + c;
            if (d < d1) { d2 = d1; i2 = i1; d1 = d; i1 = code; }
            else if (d < d2) { d2 = d; i2 = code; }
        }

        sd1[w][lane] = d1; si1[w][lane] = i1;
        sd2[w][lane] = d2; si2[w][lane] = i2;
        __syncthreads();

        // ---------- all waves: identical combine + tiered fp64 verify -------
        float bd1 = sd1[0][lane]; int bi1 = si1[0][lane]; int wstar = 0;
#pragma unroll
        for (int ww = 1; ww < 4; ++ww) {
            float dd = sd1[ww][lane]; int ii = si1[ww][lane];
            if (dd < bd1 || (dd == bd1 && ii < bi1)) { bd1 = dd; bi1 = ii; wstar = ww; }
        }
        float d2g = 3.4e38f; int i2g = 0;
#pragma unroll
        for (int ww = 0; ww < 4; ++ww) {
            float dd = (ww == wstar) ? sd2[ww][lane] : sd1[ww][lane];
            int   ii = (ww == wstar) ? si2[ww][lane] : si1[ww][lane];
            if (dd < d2g) { d2g = dd; i2g = ii; }
        }

        // tier 1: exact rank of the two global candidates (interleaved chains)
        const double* p1 = cbw + (size_t)(cbase + bi1) * 64;
        const double* p2 = cbw + (size_t)(cbase + i2g) * 64;
        double R1 = cn64[cbase + bi1];
        double R2 = cn64[cbase + i2g];
#pragma unroll 8
        for (int j = 0; j < 32; ++j) {
            d2v x = *reinterpret_cast<const d2v*>(p1 + j * 2);
            d2v y = *reinterpret_cast<const d2v*>(p2 + j * 2);
            double r0 = (double)rd[j * 2 + 0];
            double r1 = (double)rd[j * 2 + 1];
            R1 = fma(x[0], r0, R1); R1 = fma(x[1], r1, R1);
            R2 = fma(y[0], r0, R2); R2 = fma(y[1], r1, R2);
        }
        int ci; double Rw;
        if (R1 < R2 || (R1 == R2 && bi1 < i2g)) { ci = bi1; Rw = R1; }
        else                                    { ci = i2g; Rw = R2; }

        if (!(Rw < (double)d2g - EGUARD)) {
            // tier 2: exact rank of all 8 per-wave top-2 candidates
            float l8f = fminf(fminf(sd2[0][lane], sd2[1][lane]),
                              fminf(sd2[2][lane], sd2[3][lane]));
            double L8 = (double)l8f;
            double Rm = 1.0e300; int im = 0;
#pragma unroll
            for (int ww = 0; ww < 4; ++ww) {
#pragma unroll
                for (int k = 0; k < 2; ++k) {
                    int cc = k ? si2[ww][lane] : si1[ww][lane];
                    double R = rank64(cbw, cn64, cbase, cc, rd);
                    if (R < Rm || (R == Rm && cc < im)) { Rm = R; im = cc; }
                }
            }
            if (Rm < L8 - EGUARD) {
                ci = im;
            } else {
                // tier 3: full exact rescan (first-min => lowest index)
                double dmin = 1.0e300; int imin = 0;
#pragma unroll 1
                for (int c = 0; c < 256; ++c) {
                    double R = rank64(cbw, cn64, cbase, c, rd);
                    if (R < dmin) { dmin = R; imin = c; }
                }
                ci = imin;
            }
        }

        // ---------- gather q, update residual (f32, matches ref), loss ------
        const float* qp = cbf + (size_t)(cbase + ci) * 64;
        double lsse = 0.0;
#pragma unroll
        for (int q = 0; q < 16; ++q) {
            float4 qv = *reinterpret_cast<const float4*>(qp + q * 4);
            float r0 = rd[q * 4 + 0], r1 = rd[q * 4 + 1];
            float r2 = rd[q * 4 + 2], r3 = rd[q * 4 + 3];
            if (w == 0) {
                float e0 = qv.x - r0, e1 = qv.y - r1;
                float e2 = qv.z - r2, e3 = qv.w - r3;
                lsse = fma((double)e0, (double)e0, lsse);
                lsse = fma((double)e1, (double)e1, lsse);
                lsse = fma((double)e2, (double)e2, lsse);
                lsse = fma((double)e3, (double)e3, lsse);
            }
            rd[q * 4 + 0] = r0 - qv.x; rd[q * 4 + 1] = r1 - qv.y;
            rd[q * 4 + 2] = r2 - qv.z; rd[q * 4 + 3] = r3 - qv.w;
        }
        if (w == 0) {
            sse += lsse;
            codes[(size_t)lv * Ntot + grow0 + lane] = (float)ci;
        }
    }

    // ---- x_q = z - r_final ; loss partial (wave 0 only) ----
    if (w == 0) {
        size_t base = (size_t)(grow0 + lane) * 64;
#pragma unroll
        for (int q = 0; q < 16; ++q) {
            float4 zv = *reinterpret_cast<const float4*>(zr + q * 4);
            float4 o;
            o.x = zv.x - rd[q * 4 + 0];
            o.y = zv.y - rd[q * 4 + 1];
            o.z = zv.z - rd[q * 4 + 2];
            o.w = zv.w - rd[q * 4 + 3];
            *reinterpret_cast<float4*>(xq + base + q * 4) = o;
        }
        double s = sse;
#pragma unroll
        for (int off = 32; off > 0; off >>= 1) {
            union { double d; int i[2]; } u; u.d = s;
            u.i[0] = __shfl_down(u.i[0], off, 64);
            u.i[1] = __shfl_down(u.i[1], off, 64);
            s += u.d;
        }
        if (lane == 0) partials[grow0 >> 6] = s;
    }
}

// ---------------------------------------------------------------------------
__global__ void loss_final(const double* __restrict__ partials, int n,
                           float* __restrict__ out, double scale) {
    __shared__ double s[256];
    double acc = 0.0;
    for (int i = threadIdx.x; i < n; i += 256) acc += partials[i];
    s[threadIdx.x] = acc;
    __syncthreads();
    for (int off = 128; off > 0; off >>= 1) {
        if ((int)threadIdx.x < off) s[threadIdx.x] += s[threadIdx.x + off];
        __syncthreads();
    }
    if (threadIdx.x == 0) *out = (float)(s[0] * scale);
}

// ---------------------------------------------------------------------------
extern "C" void kernel_launch(void* const* d_in, const int* in_sizes, int n_in,
                              void* d_out, int out_size, void* d_ws, size_t ws_size,
                              hipStream_t stream) {
    const float* x  = (const float*)d_in[0];
    const float* W0 = (const float*)d_in[1];
    const float* b0 = (const float*)d_in[2];
    const float* W1 = (const float*)d_in[3];
    const float* b1 = (const float*)d_in[4];
    const float* W2 = (const float*)d_in[5];
    const float* b2 = (const float*)d_in[6];
    const float* cb = (const float*)d_in[7];

    const int N = in_sizes[0] / 768;

    float* out   = (float*)d_out;
    float* xq    = out;                      // [N*64]
    float* loss  = out + (size_t)N * 64;     // [1]
    float* codes = loss + 1;                 // [4*N]

    const int nblk_total = N / 64;
    // tail (float units): cbw 65536 dbl + cn64 1024 dbl + partials nblk dbl
    //                     + cnf 1024 f + pad
    const size_t tail_floats = 131072 + 2048 + 2 * (size_t)nblk_total + 1024 + 64;

    size_t avail = ws_size / 4;
    avail = (avail > tail_floats) ? (avail - tail_floats) : 0;
    int Nc = (int)(avail / 832);
    Nc = (Nc / 128) * 128;
    if (Nc > N) Nc = N;
    if (Nc < 128) Nc = 128;

    float* ws = (float*)d_ws;
    float* h0 = ws;
    float* h1 = h0 + (size_t)Nc * 512;
    float* z  = h1 + (size_t)Nc * 256;
    double* cbw      = (double*)(ws + (size_t)Nc * 832);  // 16B-aligned (Nc%128==0)
    double* cn64     = cbw + 65536;
    double* partials = cn64 + 1024;
    float*  cnf      = (float*)(partials + nblk_total);

    cb_norms <<<16, 64, 0, stream>>>(cb, cn64, cnf);
    build_cbw<<<256, 256, 0, stream>>>(cb, cbw);

    for (int r0 = 0; r0 < N; r0 += Nc) {
        int cur = (N - r0 < Nc) ? (N - r0) : Nc;
        gemm_bias<true ><<<dim3(512 / GBN, cur / GBM), 256, 0, stream>>>(
            x + (size_t)r0 * 768, W0, b0, h0, cur, 512, 768);
        gemm_bias<true ><<<dim3(256 / GBN, cur / GBM), 256, 0, stream>>>(
            h0, W1, b1, h1, cur, 256, 512);
        gemm_bias<false><<<dim3( 64 / GBN, cur / GBM), 256, 0, stream>>>(
            h1, W2, b2, z, cur, 64, 256);
        rvq_v4<<<cur / 64, 256, 0, stream>>>(
            z, cb, cbw, cn64, cnf, xq, codes, partials, r0, N);
    }

    loss_final<<<1, 256, 0, stream>>>(partials, nblk_total, loss,
                                      1.25 / (4.0 * (double)N * 64.0));
}

// Round 7
// 2822.605 us; speedup vs baseline: 1.4476x; 1.1322x over previous
//
#include <hip/hip_runtime.h>
#include <hip/hip_bf16.h>

// ---------------------------------------------------------------------------
// CRQ-VAE forward: encoder MLP (768->512->256->64, relu,relu,none) + 4-level
// residual VQ (K=256, e=64) with loss and codes.
// Outputs (flat): x_q [N*64] f32, rq_loss [1] f32, codes [4*N] f32.
// RVQ v5: f32 register scan (top-2/lane) + tiered fp64 exact verification.
// ALL residual-array indexing is compile-time static (no scratch).
// ---------------------------------------------------------------------------

typedef double d2v __attribute__((ext_vector_type(2)));

#define GBM 128
#define GBN 64
#define GBK 16
#define GTM 8
#define GTN 4

// C[M,N] = act(A[M,K] @ W[K,N] + bias[N]);  M%128==0, N%64==0, K%16==0
template<bool RELU>
__global__ __launch_bounds__(256) void gemm_bias(
    const float* __restrict__ A, const float* __restrict__ W,
    const float* __restrict__ bias, float* __restrict__ C,
    int M, int N, int K)
{
    __shared__ float As[GBK][GBM + 4];
    __shared__ float Bs[GBK][GBN + 4];

    const int tid = threadIdx.x;
    const int tx = tid & 15;
    const int ty = tid >> 4;
    const int col0 = blockIdx.x * GBN;
    const int row0 = blockIdx.y * GBM;

    const float* Ab = A + (size_t)row0 * K;
    const float* Wb = W + col0;

    float acc[GTM][GTN] = {};

    for (int k0 = 0; k0 < K; k0 += GBK) {
#pragma unroll
        for (int i = 0; i < 2; ++i) {
            int pos = tid + i * 256;
            int m  = pos >> 2;
            int k4 = (pos & 3) * 4;
            float4 v = *reinterpret_cast<const float4*>(Ab + (size_t)m * K + k0 + k4);
            As[k4 + 0][m] = v.x; As[k4 + 1][m] = v.y;
            As[k4 + 2][m] = v.z; As[k4 + 3][m] = v.w;
        }
        {
            int kk = tid >> 4;
            int n4 = (tid & 15) * 4;
            float4 v = *reinterpret_cast<const float4*>(Wb + (size_t)(k0 + kk) * N + n4);
            *reinterpret_cast<float4*>(&Bs[kk][n4]) = v;
        }
        __syncthreads();
#pragma unroll
        for (int kk = 0; kk < GBK; ++kk) {
            float4 a0 = *reinterpret_cast<const float4*>(&As[kk][ty * GTM]);
            float4 a1 = *reinterpret_cast<const float4*>(&As[kk][ty * GTM + 4]);
            float4 bv = *reinterpret_cast<const float4*>(&Bs[kk][tx * GTN]);
            float a[GTM] = {a0.x, a0.y, a0.z, a0.w, a1.x, a1.y, a1.z, a1.w};
            float b[GTN] = {bv.x, bv.y, bv.z, bv.w};
#pragma unroll
            for (int m = 0; m < GTM; ++m)
#pragma unroll
                for (int n = 0; n < GTN; ++n)
                    acc[m][n] = fmaf(a[m], b[n], acc[m][n]);
        }
        __syncthreads();
    }

    float bv[GTN];
#pragma unroll
    for (int n = 0; n < GTN; ++n) bv[n] = bias[col0 + tx * GTN + n];
#pragma unroll
    for (int m = 0; m < GTM; ++m) {
        int row = row0 + ty * GTM + m;
        float4 o;
        float v0 = acc[m][0] + bv[0];
        float v1 = acc[m][1] + bv[1];
        float v2 = acc[m][2] + bv[2];
        float v3 = acc[m][3] + bv[3];
        if (RELU) {
            v0 = fmaxf(v0, 0.f); v1 = fmaxf(v1, 0.f);
            v2 = fmaxf(v2, 0.f); v3 = fmaxf(v3, 0.f);
        }
        o.x = v0; o.y = v1; o.z = v2; o.w = v3;
        *reinterpret_cast<float4*>(C + (size_t)row * N + col0 + tx * GTN) = o;
    }
}

// ---------------------------------------------------------------------------
// codebook norms: cn64[c] (fp64) and cnf[c] (f32 rounding of cn64)
__global__ void cb_norms(const float* __restrict__ cb,
                         double* __restrict__ cn64, float* __restrict__ cnf) {
    int c = blockIdx.x * 64 + threadIdx.x;   // 16 blocks x 64
    const float* p = cb + (size_t)c * 64;
    double s = 0.0;
#pragma unroll
    for (int j = 0; j < 64; ++j) {
        double v = (double)p[j];
        s = fma(v, v, s);
    }
    cn64[c] = s;
    cnf[c]  = (float)s;
}

// widened codebook: cbw[i] = -2 * cb[i]  (same flat [4,256,64] layout, fp64)
__global__ void build_cbw(const float* __restrict__ cb, double* __restrict__ cbw) {
    int i = blockIdx.x * 256 + threadIdx.x;   // 256 blocks -> 65536
    cbw[i] = -2.0 * (double)cb[i];
}

// ---------------------------------------------------------------------------
#define EGUARD 1e-3   // >= 2.5x worst-case f32 scan error bound

// exact fp64 rank: R0 + sum_j p[j]*rd[j]; FULL unroll -> static rd indexing
__device__ __forceinline__ double rank64(const double* __restrict__ p,
                                         double R0, const float (&rd)[64]) {
    double c0 = 0.0, c1 = 0.0, c2 = 0.0, c3 = 0.0;
#pragma unroll
    for (int j = 0; j < 16; ++j) {
        d2v x = *reinterpret_cast<const d2v*>(p + j * 4);
        d2v y = *reinterpret_cast<const d2v*>(p + j * 4 + 2);
        c0 = fma(x[0], (double)rd[j * 4 + 0], c0);
        c1 = fma(x[1], (double)rd[j * 4 + 1], c1);
        c2 = fma(y[0], (double)rd[j * 4 + 2], c2);
        c3 = fma(y[1], (double)rd[j * 4 + 3], c3);
    }
    return R0 + ((c0 + c1) + (c2 + c3));
}

// RVQ v5: 64 rows/block (lane = row), 4 waves split the 256 codes.
__global__ __launch_bounds__(256, 2) void rvq_v5(
    const float* __restrict__ z,       // [cur, 64] chunk-local
    const float* __restrict__ cbf,     // [4,256,64] f32 codebook
    const double* __restrict__ cbw,    // [4,256,64] f64 (-2*cb)
    const double* __restrict__ cn64,   // [1024] f64 code norms
    const float* __restrict__ cnf,     // [1024] f32 code norms
    float* __restrict__ xq,            // d_out base [N,64]
    float* __restrict__ codes,         // d_out codes base [4,N]
    double* __restrict__ partials,     // [N/64]
    int row0, int Ntot)
{
    __shared__ float sd1[4][64];
    __shared__ float sd2[4][64];
    __shared__ int   si1[4][64];
    __shared__ int   si2[4][64];

    const int tid  = threadIdx.x;
    const int lane = tid & 63;
    const int w    = tid >> 6;
    const int wu   = __builtin_amdgcn_readfirstlane(w);   // wave-uniform
    const int blk  = blockIdx.x;
    const int grow0 = row0 + blk * 64;

    // this lane's row in registers (exact reference residual chain, f32)
    float rd[64];
    const float* zr = z + (size_t)(blk * 64 + lane) * 64;
#pragma unroll
    for (int q = 0; q < 16; ++q) {
        float4 v = *reinterpret_cast<const float4*>(zr + q * 4);
        rd[q * 4 + 0] = v.x; rd[q * 4 + 1] = v.y;
        rd[q * 4 + 2] = v.z; rd[q * 4 + 3] = v.w;
    }

    double sse = 0.0;   // wave 0 only

    for (int lv = 0; lv < 4; ++lv) {
        const int cbase = lv * 256;
        __syncthreads();   // protect sd*/si* reuse across levels

        // ---------- f32 scan over this wave's 64 codes, top-2/lane ----------
        const float* cwl = cbf + (size_t)(cbase + wu * 64) * 64;
        const float* cnl = cnf + cbase + wu * 64;

        float d1 = 3.4e38f, d2 = 3.4e38f;
        int   i1 = 0,       i2 = 0;

#pragma unroll 1
        for (int c = 0; c < 64; ++c) {
            const float* cp = cwl + c * 64;
            float acc8[8];
#pragma unroll
            for (int q = 0; q < 8; ++q) {
                float4 va = *reinterpret_cast<const float4*>(cp + q * 8);
                float4 vb = *reinterpret_cast<const float4*>(cp + q * 8 + 4);
                float t = 0.f;
                t = fmaf(va.x, rd[q * 8 + 0], t);
                t = fmaf(va.y, rd[q * 8 + 1], t);
                t = fmaf(va.z, rd[q * 8 + 2], t);
                t = fmaf(va.w, rd[q * 8 + 3], t);
                t = fmaf(vb.x, rd[q * 8 + 4], t);
                t = fmaf(vb.y, rd[q * 8 + 5], t);
                t = fmaf(vb.z, rd[q * 8 + 6], t);
                t = fmaf(vb.w, rd[q * 8 + 7], t);
                acc8[q] = t;
            }
            float dot = ((acc8[0] + acc8[1]) + (acc8[2] + acc8[3]))
                      + ((acc8[4] + acc8[5]) + (acc8[6] + acc8[7]));
            float d = fmaf(-2.f, dot, cnl[c]);
            int code = wu * 64 + c;
            if (d < d1) { d2 = d1; i2 = i1; d1 = d; i1 = code; }
            else if (d < d2) { d2 = d; i2 = code; }
        }

        sd1[w][lane] = d1; si1[w][lane] = i1;
        sd2[w][lane] = d2; si2[w][lane] = i2;
        __syncthreads();

        // ---------- all waves: identical combine + tiered fp64 verify -------
        float bd1 = sd1[0][lane]; int bi1 = si1[0][lane]; int wstar = 0;
#pragma unroll
        for (int ww = 1; ww < 4; ++ww) {
            float dd = sd1[ww][lane]; int ii = si1[ww][lane];
            if (dd < bd1 || (dd == bd1 && ii < bi1)) { bd1 = dd; bi1 = ii; wstar = ww; }
        }
        float d2g = 3.4e38f; int i2g = 0;
#pragma unroll
        for (int ww = 0; ww < 4; ++ww) {
            float dd = (ww == wstar) ? sd2[ww][lane] : sd1[ww][lane];
            int   ii = (ww == wstar) ? si2[ww][lane] : si1[ww][lane];
            if (dd < d2g) { d2g = dd; i2g = ii; }
        }

        // tier 1: exact fp64 rank of the two global candidates
        double R1 = rank64(cbw + (size_t)(cbase + bi1) * 64, cn64[cbase + bi1], rd);
        double R2 = rank64(cbw + (size_t)(cbase + i2g) * 64, cn64[cbase + i2g], rd);
        int ci; double Rw;
        if (R1 < R2 || (R1 == R2 && bi1 < i2g)) { ci = bi1; Rw = R1; }
        else                                    { ci = i2g; Rw = R2; }

        if (!(Rw < (double)d2g - EGUARD)) {
            // tier 2: exact rank of all 8 per-wave top-2 candidates
            float l8f = fminf(fminf(sd2[0][lane], sd2[1][lane]),
                              fminf(sd2[2][lane], sd2[3][lane]));
            double L8 = (double)l8f;
            double Rm = 1.0e300; int im = 0;
#pragma unroll
            for (int ww = 0; ww < 4; ++ww) {
#pragma unroll
                for (int k = 0; k < 2; ++k) {
                    int cc = k ? si2[ww][lane] : si1[ww][lane];
                    double R = rank64(cbw + (size_t)(cbase + cc) * 64,
                                      cn64[cbase + cc], rd);
                    if (R < Rm || (R == Rm && cc < im)) { Rm = R; im = cc; }
                }
            }
            if (Rm < L8 - EGUARD) {
                ci = im;
            } else {
                // tier 3: full exact rescan (first-min => lowest index)
                double dmin = 1.0e300; int imin = 0;
#pragma unroll 1
                for (int c = 0; c < 256; ++c) {
                    double R = rank64(cbw + (size_t)(cbase + c) * 64,
                                      cn64[cbase + c], rd);
                    if (R < dmin) { dmin = R; imin = c; }
                }
                ci = imin;
            }
        }

        // ---------- gather q, update residual (f32, matches ref), loss ------
        const float* qp = cbf + (size_t)(cbase + ci) * 64;
        double lsse = 0.0;
#pragma unroll
        for (int q = 0; q < 16; ++q) {
            float4 qv = *reinterpret_cast<const float4*>(qp + q * 4);
            float r0 = rd[q * 4 + 0], r1 = rd[q * 4 + 1];
            float r2 = rd[q * 4 + 2], r3 = rd[q * 4 + 3];
            if (w == 0) {
                float e0 = qv.x - r0, e1 = qv.y - r1;
                float e2 = qv.z - r2, e3 = qv.w - r3;
                lsse = fma((double)e0, (double)e0, lsse);
                lsse = fma((double)e1, (double)e1, lsse);
                lsse = fma((double)e2, (double)e2, lsse);
                lsse = fma((double)e3, (double)e3, lsse);
            }
            rd[q * 4 + 0] = r0 - qv.x; rd[q * 4 + 1] = r1 - qv.y;
            rd[q * 4 + 2] = r2 - qv.z; rd[q * 4 + 3] = r3 - qv.w;
        }
        if (w == 0) {
            sse += lsse;
            codes[(size_t)lv * Ntot + grow0 + lane] = (float)ci;
        }
    }

    // ---- x_q = z - r_final ; loss partial (wave 0 only) ----
    if (w == 0) {
        size_t base = (size_t)(grow0 + lane) * 64;
#pragma unroll
        for (int q = 0; q < 16; ++q) {
            float4 zv = *reinterpret_cast<const float4*>(zr + q * 4);
            float4 o;
            o.x = zv.x - rd[q * 4 + 0];
            o.y = zv.y - rd[q * 4 + 1];
            o.z = zv.z - rd[q * 4 + 2];
            o.w = zv.w - rd[q * 4 + 3];
            *reinterpret_cast<float4*>(xq + base + q * 4) = o;
        }
        double s = sse;
#pragma unroll
        for (int off = 32; off > 0; off >>= 1) {
            union { double d; int i[2]; } u; u.d = s;
            u.i[0] = __shfl_down(u.i[0], off, 64);
            u.i[1] = __shfl_down(u.i[1], off, 64);
            s += u.d;
        }
        if (lane == 0) partials[grow0 >> 6] = s;
    }
}

// ---------------------------------------------------------------------------
__global__ void loss_final(const double* __restrict__ partials, int n,
                           float* __restrict__ out, double scale) {
    __shared__ double s[256];
    double acc = 0.0;
    for (int i = threadIdx.x; i < n; i += 256) acc += partials[i];
    s[threadIdx.x] = acc;
    __syncthreads();
    for (int off = 128; off > 0; off >>= 1) {
        if ((int)threadIdx.x < off) s[threadIdx.x] += s[threadIdx.x + off];
        __syncthreads();
    }
    if (threadIdx.x == 0) *out = (float)(s[0] * scale);
}

// ---------------------------------------------------------------------------
extern "C" void kernel_launch(void* const* d_in, const int* in_sizes, int n_in,
                              void* d_out, int out_size, void* d_ws, size_t ws_size,
                              hipStream_t stream) {
    const float* x  = (const float*)d_in[0];
    const float* W0 = (const float*)d_in[1];
    const float* b0 = (const float*)d_in[2];
    const float* W1 = (const float*)d_in[3];
    const float* b1 = (const float*)d_in[4];
    const float* W2 = (const float*)d_in[5];
    const float* b2 = (const float*)d_in[6];
    const float* cb = (const float*)d_in[7];

    const int N = in_sizes[0] / 768;

    float* out   = (float*)d_out;
    float* xq    = out;                      // [N*64]
    float* loss  = out + (size_t)N * 64;     // [1]
    float* codes = loss + 1;                 // [4*N]

    const int nblk_total = N / 64;
    // tail (float units): cbw 65536 dbl + cn64 1024 dbl + partials nblk dbl
    //                     + cnf 1024 f + pad
    const size_t tail_floats = 131072 + 2048 + 2 * (size_t)nblk_total + 1024 + 64;

    size_t avail = ws_size / 4;
    avail = (avail > tail_floats) ? (avail - tail_floats) : 0;
    int Nc = (int)(avail / 832);
    Nc = (Nc / 128) * 128;
    if (Nc > N) Nc = N;
    if (Nc < 128) Nc = 128;

    float* ws = (float*)d_ws;
    float* h0 = ws;
    float* h1 = h0 + (size_t)Nc * 512;
    float* z  = h1 + (size_t)Nc * 256;
    double* cbw      = (double*)(ws + (size_t)Nc * 832);  // 16B-aligned (Nc%128==0)
    double* cn64     = cbw + 65536;
    double* partials = cn64 + 1024;
    float*  cnf      = (float*)(partials + nblk_total);

    cb_norms <<<16, 64, 0, stream>>>(cb, cn64, cnf);
    build_cbw<<<256, 256, 0, stream>>>(cb, cbw);

    for (int r0 = 0; r0 < N; r0 += Nc) {
        int cur = (N - r0 < Nc) ? (N - r0) : Nc;
        gemm_bias<true ><<<dim3(512 / GBN, cur / GBM), 256, 0, stream>>>(
            x + (size_t)r0 * 768, W0, b0, h0, cur, 512, 768);
        gemm_bias<true ><<<dim3(256 / GBN, cur / GBM), 256, 0, stream>>>(
            h0, W1, b1, h1, cur, 256, 512);
        gemm_bias<false><<<dim3( 64 / GBN, cur / GBM), 256, 0, stream>>>(
            h1, W2, b2, z, cur, 64, 256);
        rvq_v5<<<cur / 64, 256, 0, stream>>>(
            z, cb, cbw, cn64, cnf, xq, codes, partials, r0, N);
    }

    loss_final<<<1, 256, 0, stream>>>(partials, nblk_total, loss,
                                      1.25 / (4.0 * (double)N * 64.0));
}

// Round 8
// 2668.199 us; speedup vs baseline: 1.5313x; 1.0579x over previous
//
#include <hip/hip_runtime.h>
#include <hip/hip_bf16.h>

// ---------------------------------------------------------------------------
// CRQ-VAE forward: encoder MLP (768->512->256->64, relu,relu,none) + 4-level
// residual VQ (K=256, e=64) with loss and codes.
// Outputs (flat): x_q [N*64] f32, rq_loss [1] f32, codes [4*N] f32.
// GEMM1/2: 128x128 tile, 8x8 micro (4+4 split quadrants), reg-dbuf staging.
// Accumulation order (ascending k) identical to prior rounds -> z bitwise
// stable -> RVQ codes unchanged. RVQ v5 unchanged from R7 (passing).
// ---------------------------------------------------------------------------

typedef double d2v __attribute__((ext_vector_type(2)));

// ======================= 128x128 fp32 GEMM (N%128==0) ======================
template<bool RELU>
__global__ __launch_bounds__(256) void gemm128(
    const float* __restrict__ A, const float* __restrict__ W,
    const float* __restrict__ bias, float* __restrict__ C,
    int M, int N, int K)
{
    __shared__ float As[16][132];   // [k][m]  (A transposed in LDS)
    __shared__ float Bs[16][132];   // [k][n]

    const int tid = threadIdx.x;
    const int tx = tid & 15;        // col group
    const int ty = tid >> 4;        // row group
    const int col0 = blockIdx.x * 128;
    const int row0 = blockIdx.y * 128;

    const float* Ab = A + (size_t)row0 * K;
    const float* Wb = W + col0;

    // staging positions (512 float4 per tile for each of A,B; 2 per thread)
    const int am0 = tid >> 2,          ak0 = (tid & 3) * 4;
    const int am1 = (tid + 256) >> 2,  ak1 = ((tid + 256) & 3) * 4;
    const int bk0 = tid >> 5,          bn0 = (tid & 31) * 4;
    const int bk1 = (tid + 256) >> 5,  bn1 = ((tid + 256) & 31) * 4;

    float acc[8][8] = {};

    // ---- preload tile 0 ----
    float4 sa0 = *reinterpret_cast<const float4*>(Ab + (size_t)am0 * K + ak0);
    float4 sa1 = *reinterpret_cast<const float4*>(Ab + (size_t)am1 * K + ak1);
    float4 sb0 = *reinterpret_cast<const float4*>(Wb + (size_t)bk0 * N + bn0);
    float4 sb1 = *reinterpret_cast<const float4*>(Wb + (size_t)bk1 * N + bn1);
    As[ak0 + 0][am0] = sa0.x; As[ak0 + 1][am0] = sa0.y;
    As[ak0 + 2][am0] = sa0.z; As[ak0 + 3][am0] = sa0.w;
    As[ak1 + 0][am1] = sa1.x; As[ak1 + 1][am1] = sa1.y;
    As[ak1 + 2][am1] = sa1.z; As[ak1 + 3][am1] = sa1.w;
    *reinterpret_cast<float4*>(&Bs[bk0][bn0]) = sb0;
    *reinterpret_cast<float4*>(&Bs[bk1][bn1]) = sb1;
    __syncthreads();

    for (int k0 = 0; k0 < K; k0 += 16) {
        const bool hasNext = (k0 + 16 < K);
        if (hasNext) {
            const float* An = Ab + k0 + 16;
            const float* Wn = Wb + (size_t)(k0 + 16) * N;
            sa0 = *reinterpret_cast<const float4*>(An + (size_t)am0 * K + ak0);
            sa1 = *reinterpret_cast<const float4*>(An + (size_t)am1 * K + ak1);
            sb0 = *reinterpret_cast<const float4*>(Wn + (size_t)bk0 * N + bn0);
            sb1 = *reinterpret_cast<const float4*>(Wn + (size_t)bk1 * N + bn1);
        }

#pragma unroll
        for (int kk = 0; kk < 16; ++kk) {
            float4 a0 = *reinterpret_cast<const float4*>(&As[kk][ty * 4]);
            float4 a1 = *reinterpret_cast<const float4*>(&As[kk][64 + ty * 4]);
            float4 b0 = *reinterpret_cast<const float4*>(&Bs[kk][tx * 4]);
            float4 b1 = *reinterpret_cast<const float4*>(&Bs[kk][64 + tx * 4]);
            float ar[8] = {a0.x, a0.y, a0.z, a0.w, a1.x, a1.y, a1.z, a1.w};
            float br[8] = {b0.x, b0.y, b0.z, b0.w, b1.x, b1.y, b1.z, b1.w};
#pragma unroll
            for (int m = 0; m < 8; ++m)
#pragma unroll
                for (int n = 0; n < 8; ++n)
                    acc[m][n] = fmaf(ar[m], br[n], acc[m][n]);
        }

        if (hasNext) {
            __syncthreads();
            As[ak0 + 0][am0] = sa0.x; As[ak0 + 1][am0] = sa0.y;
            As[ak0 + 2][am0] = sa0.z; As[ak0 + 3][am0] = sa0.w;
            As[ak1 + 0][am1] = sa1.x; As[ak1 + 1][am1] = sa1.y;
            As[ak1 + 2][am1] = sa1.z; As[ak1 + 3][am1] = sa1.w;
            *reinterpret_cast<float4*>(&Bs[bk0][bn0]) = sb0;
            *reinterpret_cast<float4*>(&Bs[bk1][bn1]) = sb1;
            __syncthreads();
        }
    }

    // ---- epilogue ----
    float bl[4], bh[4];
#pragma unroll
    for (int n = 0; n < 4; ++n) {
        bl[n] = bias[col0 + tx * 4 + n];
        bh[n] = bias[col0 + 64 + tx * 4 + n];
    }
#pragma unroll
    for (int half = 0; half < 2; ++half) {
#pragma unroll
        for (int r = 0; r < 4; ++r) {
            int m = half * 4 + r;
            int row = row0 + half * 64 + ty * 4 + r;
            float4 lo, hi;
            lo.x = acc[m][0] + bl[0]; lo.y = acc[m][1] + bl[1];
            lo.z = acc[m][2] + bl[2]; lo.w = acc[m][3] + bl[3];
            hi.x = acc[m][4] + bh[0]; hi.y = acc[m][5] + bh[1];
            hi.z = acc[m][6] + bh[2]; hi.w = acc[m][7] + bh[3];
            if (RELU) {
                lo.x = fmaxf(lo.x, 0.f); lo.y = fmaxf(lo.y, 0.f);
                lo.z = fmaxf(lo.z, 0.f); lo.w = fmaxf(lo.w, 0.f);
                hi.x = fmaxf(hi.x, 0.f); hi.y = fmaxf(hi.y, 0.f);
                hi.z = fmaxf(hi.z, 0.f); hi.w = fmaxf(hi.w, 0.f);
            }
            float* Cr = C + (size_t)row * N + col0;
            *reinterpret_cast<float4*>(Cr + tx * 4) = lo;
            *reinterpret_cast<float4*>(Cr + 64 + tx * 4) = hi;
        }
    }
}

// ================== 128x64 fp32 GEMM (GEMM3, N==64) ========================
template<bool RELU>
__global__ __launch_bounds__(256) void gemm_bias(
    const float* __restrict__ A, const float* __restrict__ W,
    const float* __restrict__ bias, float* __restrict__ C,
    int M, int N, int K)
{
    __shared__ float As[16][132];
    __shared__ float Bs[16][68];

    const int tid = threadIdx.x;
    const int tx = tid & 15;
    const int ty = tid >> 4;
    const int col0 = blockIdx.x * 64;
    const int row0 = blockIdx.y * 128;

    const float* Ab = A + (size_t)row0 * K;
    const float* Wb = W + col0;

    float acc[8][4] = {};

    for (int k0 = 0; k0 < K; k0 += 16) {
#pragma unroll
        for (int i = 0; i < 2; ++i) {
            int pos = tid + i * 256;
            int m  = pos >> 2;
            int k4 = (pos & 3) * 4;
            float4 v = *reinterpret_cast<const float4*>(Ab + (size_t)m * K + k0 + k4);
            As[k4 + 0][m] = v.x; As[k4 + 1][m] = v.y;
            As[k4 + 2][m] = v.z; As[k4 + 3][m] = v.w;
        }
        {
            int kk = tid >> 4;
            int n4 = (tid & 15) * 4;
            float4 v = *reinterpret_cast<const float4*>(Wb + (size_t)(k0 + kk) * N + n4);
            *reinterpret_cast<float4*>(&Bs[kk][n4]) = v;
        }
        __syncthreads();
#pragma unroll
        for (int kk = 0; kk < 16; ++kk) {
            float4 a0 = *reinterpret_cast<const float4*>(&As[kk][ty * 8]);
            float4 a1 = *reinterpret_cast<const float4*>(&As[kk][ty * 8 + 4]);
            float4 bv = *reinterpret_cast<const float4*>(&Bs[kk][tx * 4]);
            float a[8] = {a0.x, a0.y, a0.z, a0.w, a1.x, a1.y, a1.z, a1.w};
            float b[4] = {bv.x, bv.y, bv.z, bv.w};
#pragma unroll
            for (int m = 0; m < 8; ++m)
#pragma unroll
                for (int n = 0; n < 4; ++n)
                    acc[m][n] = fmaf(a[m], b[n], acc[m][n]);
        }
        __syncthreads();
    }

    float bv[4];
#pragma unroll
    for (int n = 0; n < 4; ++n) bv[n] = bias[col0 + tx * 4 + n];
#pragma unroll
    for (int m = 0; m < 8; ++m) {
        int row = row0 + ty * 8 + m;
        float4 o;
        float v0 = acc[m][0] + bv[0];
        float v1 = acc[m][1] + bv[1];
        float v2 = acc[m][2] + bv[2];
        float v3 = acc[m][3] + bv[3];
        if (RELU) {
            v0 = fmaxf(v0, 0.f); v1 = fmaxf(v1, 0.f);
            v2 = fmaxf(v2, 0.f); v3 = fmaxf(v3, 0.f);
        }
        o.x = v0; o.y = v1; o.z = v2; o.w = v3;
        *reinterpret_cast<float4*>(C + (size_t)row * N + col0 + tx * 4) = o;
    }
}

// ---------------------------------------------------------------------------
// codebook norms: cn64[c] (fp64) and cnf[c] (f32 rounding of cn64)
__global__ void cb_norms(const float* __restrict__ cb,
                         double* __restrict__ cn64, float* __restrict__ cnf) {
    int c = blockIdx.x * 64 + threadIdx.x;   // 16 blocks x 64
    const float* p = cb + (size_t)c * 64;
    double s = 0.0;
#pragma unroll
    for (int j = 0; j < 64; ++j) {
        double v = (double)p[j];
        s = fma(v, v, s);
    }
    cn64[c] = s;
    cnf[c]  = (float)s;
}

// widened codebook: cbw[i] = -2 * cb[i]  (same flat [4,256,64] layout, fp64)
__global__ void build_cbw(const float* __restrict__ cb, double* __restrict__ cbw) {
    int i = blockIdx.x * 256 + threadIdx.x;   // 256 blocks -> 65536
    cbw[i] = -2.0 * (double)cb[i];
}

// ---------------------------------------------------------------------------
#define EGUARD 1e-3   // >= 2.5x worst-case f32 scan error bound

// exact fp64 rank: R0 + sum_j p[j]*rd[j]; FULL unroll -> static rd indexing
__device__ __forceinline__ double rank64(const double* __restrict__ p,
                                         double R0, const float (&rd)[64]) {
    double c0 = 0.0, c1 = 0.0, c2 = 0.0, c3 = 0.0;
#pragma unroll
    for (int j = 0; j < 16; ++j) {
        d2v x = *reinterpret_cast<const d2v*>(p + j * 4);
        d2v y = *reinterpret_cast<const d2v*>(p + j * 4 + 2);
        c0 = fma(x[0], (double)rd[j * 4 + 0], c0);
        c1 = fma(x[1], (double)rd[j * 4 + 1], c1);
        c2 = fma(y[0], (double)rd[j * 4 + 2], c2);
        c3 = fma(y[1], (double)rd[j * 4 + 3], c3);
    }
    return R0 + ((c0 + c1) + (c2 + c3));
}

// RVQ v5: 64 rows/block (lane = row), 4 waves split the 256 codes.
__global__ __launch_bounds__(256, 2) void rvq_v5(
    const float* __restrict__ z,       // [cur, 64] chunk-local
    const float* __restrict__ cbf,     // [4,256,64] f32 codebook
    const double* __restrict__ cbw,    // [4,256,64] f64 (-2*cb)
    const double* __restrict__ cn64,   // [1024] f64 code norms
    const float* __restrict__ cnf,     // [1024] f32 code norms
    float* __restrict__ xq,            // d_out base [N,64]
    float* __restrict__ codes,         // d_out codes base [4,N]
    double* __restrict__ partials,     // [N/64]
    int row0, int Ntot)
{
    __shared__ float sd1[4][64];
    __shared__ float sd2[4][64];
    __shared__ int   si1[4][64];
    __shared__ int   si2[4][64];

    const int tid  = threadIdx.x;
    const int lane = tid & 63;
    const int w    = tid >> 6;
    const int wu   = __builtin_amdgcn_readfirstlane(w);   // wave-uniform
    const int blk  = blockIdx.x;
    const int grow0 = row0 + blk * 64;

    float rd[64];
    const float* zr = z + (size_t)(blk * 64 + lane) * 64;
#pragma unroll
    for (int q = 0; q < 16; ++q) {
        float4 v = *reinterpret_cast<const float4*>(zr + q * 4);
        rd[q * 4 + 0] = v.x; rd[q * 4 + 1] = v.y;
        rd[q * 4 + 2] = v.z; rd[q * 4 + 3] = v.w;
    }

    double sse = 0.0;   // wave 0 only

    for (int lv = 0; lv < 4; ++lv) {
        const int cbase = lv * 256;
        __syncthreads();

        const float* cwl = cbf + (size_t)(cbase + wu * 64) * 64;
        const float* cnl = cnf + cbase + wu * 64;

        float d1 = 3.4e38f, d2 = 3.4e38f;
        int   i1 = 0,       i2 = 0;

#pragma unroll 1
        for (int c = 0; c < 64; ++c) {
            const float* cp = cwl + c * 64;
            float acc8[8];
#pragma unroll
            for (int q = 0; q < 8; ++q) {
                float4 va = *reinterpret_cast<const float4*>(cp + q * 8);
                float4 vb = *reinterpret_cast<const float4*>(cp + q * 8 + 4);
                float t = 0.f;
                t = fmaf(va.x, rd[q * 8 + 0], t);
                t = fmaf(va.y, rd[q * 8 + 1], t);
                t = fmaf(va.z, rd[q * 8 + 2], t);
                t = fmaf(va.w, rd[q * 8 + 3], t);
                t = fmaf(vb.x, rd[q * 8 + 4], t);
                t = fmaf(vb.y, rd[q * 8 + 5], t);
                t = fmaf(vb.z, rd[q * 8 + 6], t);
                t = fmaf(vb.w, rd[q * 8 + 7], t);
                acc8[q] = t;
            }
            float dot = ((acc8[0] + acc8[1]) + (acc8[2] + acc8[3]))
                      + ((acc8[4] + acc8[5]) + (acc8[6] + acc8[7]));
            float d = fmaf(-2.f, dot, cnl[c]);
            int code = wu * 64 + c;
            if (d < d1) { d2 = d1; i2 = i1; d1 = d; i1 = code; }
            else if (d < d2) { d2 = d; i2 = code; }
        }

        sd1[w][lane] = d1; si1[w][lane] = i1;
        sd2[w][lane] = d2; si2[w][lane] = i2;
        __syncthreads();

        float bd1 = sd1[0][lane]; int bi1 = si1[0][lane]; int wstar = 0;
#pragma unroll
        for (int ww = 1; ww < 4; ++ww) {
            float dd = sd1[ww][lane]; int ii = si1[ww][lane];
            if (dd < bd1 || (dd == bd1 && ii < bi1)) { bd1 = dd; bi1 = ii; wstar = ww; }
        }
        float d2g = 3.4e38f; int i2g = 0;
#pragma unroll
        for (int ww = 0; ww < 4; ++ww) {
            float dd = (ww == wstar) ? sd2[ww][lane] : sd1[ww][lane];
            int   ii = (ww == wstar) ? si2[ww][lane] : si1[ww][lane];
            if (dd < d2g) { d2g = dd; i2g = ii; }
        }

        double R1 = rank64(cbw + (size_t)(cbase + bi1) * 64, cn64[cbase + bi1], rd);
        double R2 = rank64(cbw + (size_t)(cbase + i2g) * 64, cn64[cbase + i2g], rd);
        int ci; double Rw;
        if (R1 < R2 || (R1 == R2 && bi1 < i2g)) { ci = bi1; Rw = R1; }
        else                                    { ci = i2g; Rw = R2; }

        if (!(Rw < (double)d2g - EGUARD)) {
            float l8f = fminf(fminf(sd2[0][lane], sd2[1][lane]),
                              fminf(sd2[2][lane], sd2[3][lane]));
            double L8 = (double)l8f;
            double Rm = 1.0e300; int im = 0;
#pragma unroll
            for (int ww = 0; ww < 4; ++ww) {
#pragma unroll
                for (int k = 0; k < 2; ++k) {
                    int cc = k ? si2[ww][lane] : si1[ww][lane];
                    double R = rank64(cbw + (size_t)(cbase + cc) * 64,
                                      cn64[cbase + cc], rd);
                    if (R < Rm || (R == Rm && cc < im)) { Rm = R; im = cc; }
                }
            }
            if (Rm < L8 - EGUARD) {
                ci = im;
            } else {
                double dmin = 1.0e300; int imin = 0;
#pragma unroll 1
                for (int c = 0; c < 256; ++c) {
                    double R = rank64(cbw + (size_t)(cbase + c) * 64,
                                      cn64[cbase + c], rd);
                    if (R < dmin) { dmin = R; imin = c; }
                }
                ci = imin;
            }
        }

        const float* qp = cbf + (size_t)(cbase + ci) * 64;
        double lsse = 0.0;
#pragma unroll
        for (int q = 0; q < 16; ++q) {
            float4 qv = *reinterpret_cast<const float4*>(qp + q * 4);
            float r0 = rd[q * 4 + 0], r1 = rd[q * 4 + 1];
            float r2 = rd[q * 4 + 2], r3 = rd[q * 4 + 3];
            if (w == 0) {
                float e0 = qv.x - r0, e1 = qv.y - r1;
                float e2 = qv.z - r2, e3 = qv.w - r3;
                lsse = fma((double)e0, (double)e0, lsse);
                lsse = fma((double)e1, (double)e1, lsse);
                lsse = fma((double)e2, (double)e2, lsse);
                lsse = fma((double)e3, (double)e3, lsse);
            }
            rd[q * 4 + 0] = r0 - qv.x; rd[q * 4 + 1] = r1 - qv.y;
            rd[q * 4 + 2] = r2 - qv.z; rd[q * 4 + 3] = r3 - qv.w;
        }
        if (w == 0) {
            sse += lsse;
            codes[(size_t)lv * Ntot + grow0 + lane] = (float)ci;
        }
    }

    if (w == 0) {
        size_t base = (size_t)(grow0 + lane) * 64;
#pragma unroll
        for (int q = 0; q < 16; ++q) {
            float4 zv = *reinterpret_cast<const float4*>(zr + q * 4);
            float4 o;
            o.x = zv.x - rd[q * 4 + 0];
            o.y = zv.y - rd[q * 4 + 1];
            o.z = zv.z - rd[q * 4 + 2];
            o.w = zv.w - rd[q * 4 + 3];
            *reinterpret_cast<float4*>(xq + base + q * 4) = o;
        }
        double s = sse;
#pragma unroll
        for (int off = 32; off > 0; off >>= 1) {
            union { double d; int i[2]; } u; u.d = s;
            u.i[0] = __shfl_down(u.i[0], off, 64);
            u.i[1] = __shfl_down(u.i[1], off, 64);
            s += u.d;
        }
        if (lane == 0) partials[grow0 >> 6] = s;
    }
}

// ---------------------------------------------------------------------------
__global__ void loss_final(const double* __restrict__ partials, int n,
                           float* __restrict__ out, double scale) {
    __shared__ double s[256];
    double acc = 0.0;
    for (int i = threadIdx.x; i < n; i += 256) acc += partials[i];
    s[threadIdx.x] = acc;
    __syncthreads();
    for (int off = 128; off > 0; off >>= 1) {
        if ((int)threadIdx.x < off) s[threadIdx.x] += s[threadIdx.x + off];
        __syncthreads();
    }
    if (threadIdx.x == 0) *out = (float)(s[0] * scale);
}

// ---------------------------------------------------------------------------
extern "C" void kernel_launch(void* const* d_in, const int* in_sizes, int n_in,
                              void* d_out, int out_size, void* d_ws, size_t ws_size,
                              hipStream_t stream) {
    const float* x  = (const float*)d_in[0];
    const float* W0 = (const float*)d_in[1];
    const float* b0 = (const float*)d_in[2];
    const float* W1 = (const float*)d_in[3];
    const float* b1 = (const float*)d_in[4];
    const float* W2 = (const float*)d_in[5];
    const float* b2 = (const float*)d_in[6];
    const float* cb = (const float*)d_in[7];

    const int N = in_sizes[0] / 768;

    float* out   = (float*)d_out;
    float* xq    = out;                      // [N*64]
    float* loss  = out + (size_t)N * 64;     // [1]
    float* codes = loss + 1;                 // [4*N]

    const int nblk_total = N / 64;
    const size_t tail_floats = 131072 + 2048 + 2 * (size_t)nblk_total + 1024 + 64;

    size_t avail = ws_size / 4;
    avail = (avail > tail_floats) ? (avail - tail_floats) : 0;
    int Nc = (int)(avail / 832);
    Nc = (Nc / 128) * 128;
    if (Nc > N) Nc = N;
    if (Nc < 128) Nc = 128;

    float* ws = (float*)d_ws;
    float* h0 = ws;
    float* h1 = h0 + (size_t)Nc * 512;
    float* z  = h1 + (size_t)Nc * 256;
    double* cbw      = (double*)(ws + (size_t)Nc * 832);  // 16B-aligned (Nc%128==0)
    double* cn64     = cbw + 65536;
    double* partials = cn64 + 1024;
    float*  cnf      = (float*)(partials + nblk_total);

    cb_norms <<<16, 64, 0, stream>>>(cb, cn64, cnf);
    build_cbw<<<256, 256, 0, stream>>>(cb, cbw);

    for (int r0 = 0; r0 < N; r0 += Nc) {
        int cur = (N - r0 < Nc) ? (N - r0) : Nc;
        gemm128<true ><<<dim3(512 / 128, cur / 128), 256, 0, stream>>>(
            x + (size_t)r0 * 768, W0, b0, h0, cur, 512, 768);
        gemm128<true ><<<dim3(256 / 128, cur / 128), 256, 0, stream>>>(
            h0, W1, b1, h1, cur, 256, 512);
        gemm_bias<false><<<dim3(1, cur / 128), 256, 0, stream>>>(
            h1, W2, b2, z, cur, 64, 256);
        rvq_v5<<<cur / 64, 256, 0, stream>>>(
            z, cb, cbw, cn64, cnf, xq, codes, partials, r0, N);
    }

    loss_final<<<1, 256, 0, stream>>>(partials, nblk_total, loss,
                                      1.25 / (4.0 * (double)N * 64.0));
}